// Round 5
// baseline (494.566 us; speedup 1.0000x reference)
//
#include <hip/hip_runtime.h>
#include <hip/hip_bf16.h>
#include <math.h>

#define N_GENE 50000
#define N_DIS  25000
#define F_GENE 512
#define F_DIS  256
#define E_EDGES 150000
#define BN_EPS 1e-5f

typedef unsigned short u16;
typedef unsigned int u32;
typedef short s16x8 __attribute__((ext_vector_type(8)));
typedef float f32x4 __attribute__((ext_vector_type(4)));

__device__ __forceinline__ u16 f2bf(float f) {
    union { float f; unsigned u; } c; c.f = f;
    unsigned u = c.u;
    unsigned rounding = 0x7FFFu + ((u >> 16) & 1u);
    return (u16)((u + rounding) >> 16);
}
__device__ __forceinline__ void load_bf16x8(const u16* p, float* f) {
    uint4 q = *reinterpret_cast<const uint4*>(p);
    unsigned w0 = q.x, w1 = q.y, w2 = q.z, w3 = q.w;
    f[0] = __uint_as_float(w0 << 16); f[1] = __uint_as_float(w0 & 0xffff0000u);
    f[2] = __uint_as_float(w1 << 16); f[3] = __uint_as_float(w1 & 0xffff0000u);
    f[4] = __uint_as_float(w2 << 16); f[5] = __uint_as_float(w2 & 0xffff0000u);
    f[6] = __uint_as_float(w3 << 16); f[7] = __uint_as_float(w3 & 0xffff0000u);
}

// ---- B pack helper: W f32 [K][N] -> fragment-major bf16 Bp[nt][KC][64][8]
__device__ __forceinline__ void pack_one(const float* __restrict__ W, u16* __restrict__ Bp,
                                         int K, int N, int i) {
    int K8 = K >> 3;
    int n = i / K8, ko = i - n * K8;
    int k0 = ko * 8;
    int nt = n >> 4, mr = n & 15, kc = k0 >> 5, quad = (k0 >> 3) & 3;
    u16 tmp[8];
#pragma unroll
    for (int j = 0; j < 8; j++) tmp[j] = f2bf(W[(size_t)(k0 + j) * N + n]);
    *reinterpret_cast<uint4*>(&Bp[((size_t)(nt * (K >> 5) + kc) * 64 + quad * 16 + mr) * 8]) =
        *reinterpret_cast<const uint4*>(tmp);
}

// ---- one front-kernel: all weight packs + all zero-fills + both weff vectors ----
__global__ void prep(const float* __restrict__ Wg, const float* __restrict__ Wd,
                     const float* __restrict__ W1s, const float* __restrict__ W2s,
                     u16* __restrict__ Wgt, u16* __restrict__ Wdt,
                     u16* __restrict__ W1st, u16* __restrict__ W2st,
                     float* __restrict__ stats_g, float* __restrict__ stats_d,
                     int* __restrict__ deg1, int* __restrict__ deg2,
                     const float* __restrict__ W1d, const float* __restrict__ a1d,
                     const float* __restrict__ W2d, const float* __restrict__ a2d,
                     float* __restrict__ weff) {
    int i = blockIdx.x * 256 + threadIdx.x;
    if (i < 8192) { pack_one(Wg, Wgt, 512, 128, i); return; }
    i -= 8192;
    if (i < 4096) { pack_one(Wd, Wdt, 256, 128, i); return; }
    i -= 4096;
    if (i < 8192) { pack_one(W1s, W1st, 128, 512, i); return; }
    i -= 8192;
    if (i < 8192) { pack_one(W2s, W2st, 128, 512, i); return; }
    i -= 8192;
    if (i < 256) { stats_g[i] = 0.f; return; }
    i -= 256;
    if (i < 256) { stats_d[i] = 0.f; return; }
    i -= 256;
    if (i < N_GENE) { deg1[i] = 0; return; }
    i -= N_GENE;
    if (i < N_GENE) { deg2[i] = 0; return; }
    i -= N_GENE;
    if (i < 1024) {
        int rel = i >> 9, tt = i & 511;
        int h = tt >> 7, k = tt & 127;
        const float* Wp = rel ? W2d : W1d;
        const float* ap = rel ? a2d : a1d;
        float s = 0.f;
        for (int c = 0; c < 128; c++) s += Wp[k * 512 + h * 128 + c] * ap[h * 128 + c];
        weff[rel * 512 + h * 128 + k] = s;
    }
}

// ---- GEMM, barrier-free register version: each wave owns 16 rows x 128 cols.
// B fragments read per-wave straight from global (L2-hot: identical 128KB slab for all
// blocks). Double-buffered named register sets, no LDS staging, no s_barrier -> waves
// slip freely and TLP+ILP hides latency. Fused epilogues: BN stats / ls attention dot.
template <int K, bool A_FRAG, bool RELU_BIAS, bool OUT_BF16, bool FUSE_STATS, bool FUSE_LS>
__global__ __launch_bounds__(256) void gemm_reg(const void* __restrict__ Ap,
                                                const u16* __restrict__ Bp,
                                                const float* __restrict__ bias,
                                                void* __restrict__ outp, int M, int NFULL,
                                                float* __restrict__ stats,
                                                const float* __restrict__ as_,
                                                float* __restrict__ ls_out) {
    constexpr int KC = K / 32;          // 16 / 8 / 4 (always even)
    __shared__ float sstat[256];
    const int wave = threadIdx.x >> 6;
    const int lane = threadIdx.x & 63;
    const int mrow = lane & 15;
    const int quad = lane >> 4;
    const int wid = blockIdx.x * 4 + wave;     // global wave id, 16 rows each
    const int m0 = wid * 16;
    const int n0 = blockIdx.y * 128;
    const int arow = (m0 + mrow < M) ? m0 + mrow : M - 1;
    const int rt = (m0 >> 4) < ((M + 15) >> 4) ? (m0 >> 4) : ((M + 15) >> 4) - 1;
    const u16* bslab = Bp + (size_t)(n0 >> 4) * KC * 512;  // 512 u16 per frag

    if constexpr (FUSE_STATS) sstat[threadIdx.x] = 0.f;  // 256 threads exactly

    f32x4 acc[8];
#pragma unroll
    for (int t = 0; t < 8; t++) acc[t] = (f32x4){0.f, 0.f, 0.f, 0.f};

    struct BRegs { s16x8 b[8]; };
    struct ARegs { float4 f[2]; s16x8 s; };
    BRegs B0, B1;
    ARegs A0, A1;

    auto loadB = [&](int kc, BRegs& B) {
#pragma unroll
        for (int t = 0; t < 8; t++)
            B.b[t] = *reinterpret_cast<const s16x8*>(
                bslab + ((size_t)(t * KC + kc) * 64 + lane) * 8);
    };
    auto loadA = [&](int kc, ARegs& A) {
        if constexpr (A_FRAG) {
            A.s = *reinterpret_cast<const s16x8*>(
                (const u16*)Ap + ((size_t)(rt * KC + kc) * 64 + lane) * 8);
        } else {
            const float* ap = (const float*)Ap + (size_t)arow * K + kc * 32 + quad * 8;
            A.f[0] = *reinterpret_cast<const float4*>(ap);
            A.f[1] = *reinterpret_cast<const float4*>(ap + 4);
        }
    };
    auto compute = [&](const BRegs& B, const ARegs& A) {
        s16x8 af;
        if constexpr (A_FRAG) {
            af = A.s;
        } else {
            const float4 lo = A.f[0], hi = A.f[1];
            af[0] = (short)f2bf(lo.x); af[1] = (short)f2bf(lo.y);
            af[2] = (short)f2bf(lo.z); af[3] = (short)f2bf(lo.w);
            af[4] = (short)f2bf(hi.x); af[5] = (short)f2bf(hi.y);
            af[6] = (short)f2bf(hi.z); af[7] = (short)f2bf(hi.w);
        }
#pragma unroll
        for (int t = 0; t < 8; t++)
            acc[t] = __builtin_amdgcn_mfma_f32_16x16x32_bf16(af, B.b[t], acc[t], 0, 0, 0);
    };

    loadB(0, B0);
    loadA(0, A0);
#pragma unroll
    for (int kc = 0; kc < KC; kc += 2) {
        if (kc + 1 < KC) { loadB(kc + 1, B1); loadA(kc + 1, A1); }
        compute(B0, A0);
        if (kc + 2 < KC) { loadB(kc + 2, B0); loadA(kc + 2, A0); }
        if (kc + 1 < KC) compute(B1, A1);
    }

    float asv[8];
    if constexpr (FUSE_LS) {
        const int h = blockIdx.y;
#pragma unroll
        for (int t = 0; t < 8; t++) asv[t] = as_[h * 128 + t * 16 + mrow];
    }
    float lsp[4] = {0.f, 0.f, 0.f, 0.f};

#pragma unroll
    for (int t = 0; t < 8; t++) {
        int col = n0 + t * 16 + mrow;
        float sv = 0.f, sv2 = 0.f;
#pragma unroll
        for (int r = 0; r < 4; r++) {
            int orow = m0 + quad * 4 + r;
            if (orow < M) {
                float v = acc[t][r];
                if (RELU_BIAS) v = fmaxf(v + bias[col], 0.f);
                if (OUT_BF16)
                    ((u16*)outp)[(size_t)orow * NFULL + col] = f2bf(v);
                else
                    ((float*)outp)[(size_t)orow * NFULL + col] = v;
                if constexpr (FUSE_STATS) { sv += v; sv2 += v * v; }
                if constexpr (FUSE_LS) lsp[r] += v * asv[t];
            }
        }
        if constexpr (FUSE_STATS) {
            sv  += __shfl_xor(sv, 16, 64);  sv  += __shfl_xor(sv, 32, 64);
            sv2 += __shfl_xor(sv2, 16, 64); sv2 += __shfl_xor(sv2, 32, 64);
            if (quad == 0) {
                atomicAdd(&sstat[t * 16 + mrow], sv);
                atomicAdd(&sstat[128 + t * 16 + mrow], sv2);
            }
        }
    }
    if constexpr (FUSE_LS) {
        const int h = blockIdx.y;
#pragma unroll
        for (int r = 0; r < 4; r++) {
            float p = lsp[r];
            p += __shfl_xor(p, 1, 64); p += __shfl_xor(p, 2, 64);
            p += __shfl_xor(p, 4, 64); p += __shfl_xor(p, 8, 64);
            int orow = m0 + quad * 4 + r;
            if (mrow == 0 && orow < M) ls_out[orow * 4 + h] = p;
        }
    }
    if constexpr (FUSE_STATS) {
        __syncthreads();
        atomicAdd(&stats[threadIdx.x], sstat[threadIdx.x]);  // 256 threads
    }
}

// bn in place; optional bf16 fragment-major mirror; optional fused ld (dst attention dot)
__global__ void bn_apply(float* __restrict__ X, const float* __restrict__ stats,
                         const float* __restrict__ gamma, const float* __restrict__ beta,
                         u16* __restrict__ mirror, const float* __restrict__ weff,
                         float* __restrict__ ld_out, int M) {
    int i = blockIdx.x * 256 + threadIdx.x;   // M*16 threads, 8 cols each
    if (i >= M * 16) return;
    int row = i >> 4, cg = i & 15;
    float inv_m = 1.0f / (float)M;
    float4 lo = *reinterpret_cast<const float4*>(&X[(size_t)row * 128 + cg * 8]);
    float4 hi = *reinterpret_cast<const float4*>(&X[(size_t)row * 128 + cg * 8 + 4]);
    float v[8] = {lo.x, lo.y, lo.z, lo.w, hi.x, hi.y, hi.z, hi.w};
    u16 mb[8];
#pragma unroll
    for (int e = 0; e < 8; e++) {
        int col = cg * 8 + e;
        float mu = stats[col] * inv_m;
        float var = stats[128 + col] * inv_m - mu * mu;
        v[e] = gamma[col] * (v[e] - mu) * rsqrtf(var + BN_EPS) + beta[col];
        mb[e] = f2bf(v[e]);
    }
    *reinterpret_cast<float4*>(&X[(size_t)row * 128 + cg * 8]) = (float4){v[0], v[1], v[2], v[3]};
    *reinterpret_cast<float4*>(&X[(size_t)row * 128 + cg * 8 + 4]) = (float4){v[4], v[5], v[6], v[7]};
    if (mirror) {
        int kc = cg >> 2, quad = cg & 3, ml = quad * 16 + (row & 15), rt = row >> 4;
        *reinterpret_cast<uint4*>(&mirror[((size_t)(rt * 4 + kc) * 64 + ml) * 8]) =
            *reinterpret_cast<const uint4*>(mb);
    }
    if (ld_out) {
#pragma unroll
        for (int h = 0; h < 4; h++) {
            float p = 0.f;
#pragma unroll
            for (int e = 0; e < 8; e++) p += v[e] * weff[h * 128 + cg * 8 + e];
            p += __shfl_xor(p, 1, 64); p += __shfl_xor(p, 2, 64);
            p += __shfl_xor(p, 4, 64); p += __shfl_xor(p, 8, 64);
            if (cg == 0) ld_out[row * 4 + h] = p;
        }
    }
}

// ---------------- CSR build (both relations) ----------------
__global__ void count_both(const int* __restrict__ e1s, const int* __restrict__ e1d,
                           const int* __restrict__ e2s, const int* __restrict__ e2d,
                           int* __restrict__ deg1, int* __restrict__ deg2) {
    int i = blockIdx.x * 256 + threadIdx.x;
    if (i < E_EDGES + N_DIS) {
        int d;
        if (i < E_EDGES) { int s = e1s[i]; d = e1d[i]; if (s == d) return; }
        else d = i - E_EDGES;
        atomicAdd(&deg1[d], 1);
        return;
    }
    i -= E_EDGES + N_DIS;
    if (i < E_EDGES + N_GENE) {
        int d;
        if (i < E_EDGES) { int s = e2s[i]; d = e2d[i]; if (s == d) return; }
        else d = i - E_EDGES;
        atomicAdd(&deg2[d], 1);
    }
}

// 3-phase scan, both relations in one grid (blocks [0,NB) rel1, [NB,2NB) rel2)
__global__ void block_sum_both(const int* __restrict__ deg1, const int* __restrict__ deg2,
                               int* __restrict__ bsum, int nb) {
    __shared__ int sh[256];
    int rel = blockIdx.x >= nb;
    int blk = rel ? blockIdx.x - nb : blockIdx.x;
    const int* deg = rel ? deg2 : deg1;
    int i = blk * 256 + threadIdx.x;
    sh[threadIdx.x] = (i < N_GENE) ? deg[i] : 0;
    __syncthreads();
    for (int s = 128; s > 0; s >>= 1) {
        if (threadIdx.x < s) sh[threadIdx.x] += sh[threadIdx.x + s];
        __syncthreads();
    }
    if (threadIdx.x == 0) bsum[blockIdx.x] = sh[0];
}

__global__ void scan_bsum_both(int* __restrict__ bsum, int nb,
                               int* __restrict__ offs1, int* __restrict__ offs2) {
    __shared__ int sh[256];
    int* bs = bsum + blockIdx.x * nb;
    int tid = threadIdx.x;
    int v = (tid < nb) ? bs[tid] : 0;
    sh[tid] = v;
    __syncthreads();
    for (int off = 1; off < 256; off <<= 1) {
        int t = (tid >= off) ? sh[tid - off] : 0;
        __syncthreads();
        sh[tid] += t;
        __syncthreads();
    }
    if (tid < nb) bs[tid] = sh[tid] - v;   // exclusive
    if (tid == 255) (blockIdx.x ? offs2 : offs1)[N_GENE] = sh[255];
}

__global__ void scan_final_both(const int* __restrict__ deg1, const int* __restrict__ deg2,
                                const int* __restrict__ bsum, int nb,
                                int* __restrict__ offs1, int* __restrict__ cur1,
                                int* __restrict__ offs2, int* __restrict__ cur2) {
    __shared__ int sh[256];
    int rel = blockIdx.x >= nb;
    int blk = rel ? blockIdx.x - nb : blockIdx.x;
    const int* deg = rel ? deg2 : deg1;
    int* offs = rel ? offs2 : offs1;
    int* cur  = rel ? cur2  : cur1;
    int i = blk * 256 + threadIdx.x, tid = threadIdx.x;
    int v = (i < N_GENE) ? deg[i] : 0;
    sh[tid] = v;
    __syncthreads();
    for (int off = 1; off < 256; off <<= 1) {
        int t = (tid >= off) ? sh[tid - off] : 0;
        __syncthreads();
        sh[tid] += t;
        __syncthreads();
    }
    int ex = bsum[blockIdx.x] + sh[tid] - v;
    if (i < N_GENE) { offs[i] = ex; cur[i] = ex; }
}

__global__ void scatter_both(const int* __restrict__ e1s, const int* __restrict__ e1d,
                             const int* __restrict__ e2s, const int* __restrict__ e2d,
                             int* __restrict__ cur1, int* __restrict__ cur2,
                             int* __restrict__ esrc1, int* __restrict__ esrc2) {
    int i = blockIdx.x * 256 + threadIdx.x;
    if (i < E_EDGES + N_DIS) {
        int s, d;
        if (i < E_EDGES) { s = e1s[i]; d = e1d[i]; if (s == d) return; }
        else { s = i - E_EDGES; d = s; }
        esrc1[atomicAdd(&cur1[d], 1)] = s;
        return;
    }
    i -= E_EDGES + N_DIS;
    if (i < E_EDGES + N_GENE) {
        int s, d;
        if (i < E_EDGES) { s = e2s[i]; d = e2d[i]; if (s == d) return; }
        else { s = i - E_EDGES; d = s; }
        esrc2[atomicAdd(&cur2[d], 1)] = s;
    }
}

// ---- GAT aggregation: one wave per dst node; updates xdst_out in place ----
// optional fused: ld for NEXT relation (from updated row), bf16 fragment-major mirror
__global__ void gat_kernel(const int* __restrict__ offs, const int* __restrict__ esrc,
                           const float* __restrict__ ls, const float* __restrict__ ld,
                           const u16* __restrict__ xs, const float* __restrict__ bias,
                           float* __restrict__ xdst_out, u16* __restrict__ mirror,
                           const float* __restrict__ weff2, float* __restrict__ ld2_out,
                           int n_dst) {
    int wid = (blockIdx.x * blockDim.x + threadIdx.x) >> 6;
    int lane = threadIdx.x & 63;
    if (wid >= n_dst) return;
    int h = lane >> 4;
    int beg = offs[wid], end = offs[wid + 1];
    float ldv = ld[wid * 4 + h];
    float m = -INFINITY;
    for (int j = beg; j < end; j++) {
        int s = esrc[j];
        float l = ls[s * 4 + h] + ldv;
        l = l > 0.f ? l : 0.2f * l;
        m = fmaxf(m, l);
    }
    float denom = 0.f;
    float acc[8] = {0.f, 0.f, 0.f, 0.f, 0.f, 0.f, 0.f, 0.f};
    for (int j = beg; j < end; j++) {
        int s = esrc[j];
        float l = ls[s * 4 + h] + ldv;
        l = l > 0.f ? l : 0.2f * l;
        float p = __expf(l - m);
        denom += p;
        float xv[8];
        load_bf16x8(xs + (size_t)s * 512 + lane * 8, xv);
        #pragma unroll
        for (int k = 0; k < 8; k++) acc[k] += p * xv[k];
    }
    float dinv = denom > 0.f ? 1.f / denom : 1.f;
    #pragma unroll
    for (int k = 0; k < 8; k++) {
        float v = acc[k] * dinv;
        v += __shfl_xor(v, 16, 64);
        v += __shfl_xor(v, 32, 64);
        acc[k] = v * 0.25f;
    }
    if (lane < 16) {
        int c0 = lane * 8;
        float vout[8];
        #pragma unroll
        for (int k = 0; k < 8; k++) {
            vout[k] = xdst_out[(size_t)wid * 128 + c0 + k] + acc[k] + bias[c0 + k];
            xdst_out[(size_t)wid * 128 + c0 + k] = vout[k];
        }
        if (mirror) {
            unsigned pk[4];
            #pragma unroll
            for (int kk = 0; kk < 4; kk++)
                pk[kk] = (unsigned)f2bf(vout[2 * kk]) | ((unsigned)f2bf(vout[2 * kk + 1]) << 16);
            int kc = lane >> 2, quad = lane & 3, ml = quad * 16 + (wid & 15), rt = wid >> 4;
            *reinterpret_cast<uint4*>(&mirror[((size_t)(rt * 4 + kc) * 64 + ml) * 8]) =
                *reinterpret_cast<const uint4*>(pk);
        }
        if (weff2) {
            #pragma unroll
            for (int hh = 0; hh < 4; hh++) {
                float p = 0.f;
                #pragma unroll
                for (int k = 0; k < 8; k++) p += vout[k] * weff2[hh * 128 + c0 + k];
                p += __shfl_xor(p, 1, 64); p += __shfl_xor(p, 2, 64);
                p += __shfl_xor(p, 4, 64); p += __shfl_xor(p, 8, 64);
                if (lane == 0) ld2_out[wid * 4 + hh] = p;
            }
        }
    }
}

static inline int cdiv(int a, int b) { return (a + b - 1) / b; }

extern "C" void kernel_launch(void* const* d_in, const int* in_sizes, int n_in,
                              void* d_out, int out_size, void* d_ws, size_t ws_size,
                              hipStream_t stream) {
    const float* x_gene = (const float*)d_in[0];
    const float* x_dis  = (const float*)d_in[1];
    const int* e1s = (const int*)d_in[2];
    const int* e1d = (const int*)d_in[3];
    const int* e2s = (const int*)d_in[4];
    const int* e2d = (const int*)d_in[5];
    const float *Wg = (const float*)d_in[6],  *bg = (const float*)d_in[7];
    const float *gg = (const float*)d_in[8],  *betag = (const float*)d_in[9];
    const float *Wd = (const float*)d_in[10], *bd = (const float*)d_in[11];
    const float *gd = (const float*)d_in[12], *betad = (const float*)d_in[13];
    const float *W1s = (const float*)d_in[14], *W1d = (const float*)d_in[15];
    const float *a1s = (const float*)d_in[16], *a1d = (const float*)d_in[17];
    const float *b1  = (const float*)d_in[18];
    const float *W2s = (const float*)d_in[19], *W2d = (const float*)d_in[20];
    const float *a2s = (const float*)d_in[21], *a2d = (const float*)d_in[22];
    const float *b2  = (const float*)d_in[23];

    float* gene_f = (float*)d_out;                         // [N_GENE,128]
    float* dis_f  = (float*)d_out + (size_t)N_GENE * 128;  // [N_DIS,128]

    char* p = (char*)d_ws;
    auto alloc = [&](size_t bytes) {
        char* r = p;
        p += (bytes + 255) & ~(size_t)255;
        return r;
    };
    u16*   xs_buf  = (u16*)  alloc((size_t)N_GENE * 512 * 2);
    u16*   gene_bf = (u16*)  alloc((size_t)cdiv(N_GENE, 16) * 2048 * 2);
    u16*   dis_bf  = (u16*)  alloc((size_t)cdiv(N_DIS, 16) * 2048 * 2);
    float* ls_buf  = (float*)alloc((size_t)N_GENE * 4 * 4);
    float* ld1_buf = (float*)alloc((size_t)N_GENE * 4 * 4);
    float* ld2_buf = (float*)alloc((size_t)N_GENE * 4 * 4);
    float* weff    = (float*)alloc(1024 * 4);              // [rel1:512 | rel2:512]
    float* stats_g = (float*)alloc(256 * 4);
    float* stats_d = (float*)alloc(256 * 4);
    int*   deg1    = (int*)  alloc((size_t)N_GENE * 4);
    int*   deg2    = (int*)  alloc((size_t)N_GENE * 4);
    int*   offs1   = (int*)  alloc((size_t)(N_GENE + 1) * 4);
    int*   offs2   = (int*)  alloc((size_t)(N_GENE + 1) * 4);
    int*   cur1    = (int*)  alloc((size_t)N_GENE * 4);
    int*   cur2    = (int*)  alloc((size_t)N_GENE * 4);
    int*   bsum    = (int*)  alloc(512 * 4);
    int*   esrc1   = (int*)  alloc((size_t)(E_EDGES + N_GENE) * 4);
    int*   esrc2   = (int*)  alloc((size_t)(E_EDGES + N_GENE) * 4);
    u16*   Wgt  = (u16*)alloc((size_t)8 * 16 * 512 * 2);   // [8nt][16kc][512]
    u16*   Wdt  = (u16*)alloc((size_t)8 * 8 * 512 * 2);    // [8nt][8kc][512]
    u16*   W1st = (u16*)alloc((size_t)32 * 4 * 512 * 2);   // [32nt][4kc][512]
    u16*   W2st = (u16*)alloc((size_t)32 * 4 * 512 * 2);

    const int NB = cdiv(N_GENE, 256);  // 196

    // ---- front: packs + zeros + weff (1 kernel), then CSR for both relations ----
    const int PREP_T = 8192 + 4096 + 8192 + 8192 + 256 + 256 + N_GENE + N_GENE + 1024;
    prep<<<cdiv(PREP_T, 256), 256, 0, stream>>>(Wg, Wd, W1s, W2s, Wgt, Wdt, W1st, W2st,
                                                stats_g, stats_d, deg1, deg2,
                                                W1d, a1d, W2d, a2d, weff);
    const int EB = cdiv((E_EDGES + N_DIS) + (E_EDGES + N_GENE), 256);
    count_both<<<EB, 256, 0, stream>>>(e1s, e1d, e2s, e2d, deg1, deg2);
    block_sum_both<<<2 * NB, 256, 0, stream>>>(deg1, deg2, bsum, NB);
    scan_bsum_both<<<2, 256, 0, stream>>>(bsum, NB, offs1, offs2);
    scan_final_both<<<2 * NB, 256, 0, stream>>>(deg1, deg2, bsum, NB, offs1, cur1, offs2, cur2);
    scatter_both<<<EB, 256, 0, stream>>>(e1s, e1d, e2s, e2d, cur1, cur2, esrc1, esrc2);

    // ---- encode gene (stats fused into GEMM; ld1 fused into bn) ----
    gemm_reg<512, false, true, false, true, false><<<dim3(cdiv(N_GENE, 64), 1), 256, 0, stream>>>(
        x_gene, Wgt, bg, gene_f, N_GENE, 128, stats_g, nullptr, nullptr);
    bn_apply<<<cdiv(N_GENE * 16, 256), 256, 0, stream>>>(gene_f, stats_g, gg, betag,
                                                         nullptr, weff, ld1_buf, N_GENE);

    // ---- encode dis ----
    gemm_reg<256, false, true, false, true, false><<<dim3(cdiv(N_DIS, 64), 1), 256, 0, stream>>>(
        x_dis, Wdt, bd, dis_f, N_DIS, 128, stats_d, nullptr, nullptr);
    bn_apply<<<cdiv(N_DIS * 16, 256), 256, 0, stream>>>(dis_f, stats_d, gd, betad,
                                                        dis_bf, nullptr, nullptr, N_DIS);

    // ---- relation 1: Disease -> Gene (ls fused into GEMM; ld2 fused into gat) ----
    gemm_reg<128, true, false, true, false, true><<<dim3(cdiv(N_DIS, 64), 4), 256, 0, stream>>>(
        dis_bf, W1st, nullptr, xs_buf, N_DIS, 512, nullptr, a1s, ls_buf);
    gat_kernel<<<cdiv(N_GENE, 4), 256, 0, stream>>>(offs1, esrc1, ls_buf, ld1_buf, xs_buf, b1,
                                                    gene_f, gene_bf, weff + 512, ld2_buf, N_GENE);

    // ---- relation 2: Gene -> Gene ----
    gemm_reg<128, true, false, true, false, true><<<dim3(cdiv(N_GENE, 64), 4), 256, 0, stream>>>(
        gene_bf, W2st, nullptr, xs_buf, N_GENE, 512, nullptr, a2s, ls_buf);
    gat_kernel<<<cdiv(N_GENE, 4), 256, 0, stream>>>(offs2, esrc2, ls_buf, ld2_buf, xs_buf, b2,
                                                    gene_f, nullptr, nullptr, nullptr, N_GENE);
}